// Round 1
// baseline (816.159 us; speedup 1.0000x reference)
//
#include <hip/hip_runtime.h>
#include <math.h>

// ---------------- problem constants ----------------
#define DD   128          // d
#define MM   4096         // m
#define PP   8            // pooling
#define KK   2            // experts
#define NSTEP 4

// ---------------- ws float-offset layout ----------------
#define WS_H   0          // 128 floats
#define WS_C   128        // 128
#define WS_RS  896        // 128 (r for suffix s)
#define WS_RE  1024       // 128 (r for suffix e)
#define WS_GS  1152       // 4: [gs0,gs1,ge0,ge1]
#define WS_SI  1156       // int
#define WS_EI  1157       // int
#define WS_RT  2048       // 4096: [suf][k][e]
#define WS_Z0  16384      // Z0 region start (aligned)

#define NEG_INF (-3.4e38f)

// =====================================================================
// init: reset h, c, si, ei every launch (graph replays need this)
// =====================================================================
__global__ void k_init(float* __restrict__ ws) {
  int t = threadIdx.x;
  if (t < 128) { ws[WS_H + t] = 0.f; ws[WS_C + t] = 0.f; }
  if (t == 0) { ((int*)ws)[WS_SI] = 0; ((int*)ws)[WS_EI] = MM - 1; }
}

// =====================================================================
// Z0 GEMM: C[suf][k][m][e] = sum_{f<256} U[m][f] * We[suf][k][e][f]
// tile 128x128, 256 threads, 8x8 micro, KC=16
// =====================================================================
__global__ __launch_bounds__(256) void k_z0(
    const float* __restrict__ U,
    const float* __restrict__ We_s, const float* __restrict__ We_e,
    float* __restrict__ z0s, float* __restrict__ z0e, int fixed_suf) {
  __shared__ float As[16][132];
  __shared__ float Bs[16][132];
  int t  = threadIdx.x;
  int tx = t & 15, ty = t >> 4;
  int tx4 = tx * 4, ty4 = ty * 4;
  int m0 = blockIdx.x * 128, e0 = blockIdx.y * 128;
  int z = blockIdx.z;
  int suf, k;
  if (fixed_suf < 0) { suf = z >> 1; k = z & 1; }
  else               { suf = fixed_suf; k = z; }
  const float* B = (suf ? We_e : We_s) + (size_t)k * 1024 * 384;

  float acc[8][8];
#pragma unroll
  for (int i = 0; i < 8; ++i)
#pragma unroll
    for (int j = 0; j < 8; ++j) acc[i][j] = 0.f;

  for (int kc = 0; kc < 16; ++kc) {
    int f0 = kc * 16;
    __syncthreads();
    for (int l = t; l < 512; l += 256) {
      int row = l >> 2, fq = l & 3;
      float4 v = *(const float4*)&U[(size_t)(m0 + row) * 256 + f0 + fq * 4];
      As[fq*4+0][row] = v.x; As[fq*4+1][row] = v.y;
      As[fq*4+2][row] = v.z; As[fq*4+3][row] = v.w;
    }
    for (int l = t; l < 512; l += 256) {
      int row = l >> 2, fq = l & 3;
      float4 v = *(const float4*)&B[(size_t)(e0 + row) * 384 + f0 + fq * 4];
      Bs[fq*4+0][row] = v.x; Bs[fq*4+1][row] = v.y;
      Bs[fq*4+2][row] = v.z; Bs[fq*4+3][row] = v.w;
    }
    __syncthreads();
#pragma unroll
    for (int f = 0; f < 16; ++f) {
      float4 alo = *(const float4*)&As[f][ty4];
      float4 ahi = *(const float4*)&As[f][64 + ty4];
      float4 blo = *(const float4*)&Bs[f][tx4];
      float4 bhi = *(const float4*)&Bs[f][64 + tx4];
      float a_[8] = {alo.x, alo.y, alo.z, alo.w, ahi.x, ahi.y, ahi.z, ahi.w};
      float b_[8] = {blo.x, blo.y, blo.z, blo.w, bhi.x, bhi.y, bhi.z, bhi.w};
#pragma unroll
      for (int i = 0; i < 8; ++i)
#pragma unroll
        for (int j = 0; j < 8; ++j) acc[i][j] += a_[i] * b_[j];
    }
  }
  float* C = (suf ? z0e : z0s) + (size_t)k * MM * 1024;
#pragma unroll
  for (int i = 0; i < 8; ++i) {
    int row = m0 + ((i < 4) ? (ty4 + i) : (64 + ty4 + i - 4));
    float* cp = C + (size_t)row * 1024 + e0;
    *(float4*)&cp[tx4]      = make_float4(acc[i][0], acc[i][1], acc[i][2], acc[i][3]);
    *(float4*)&cp[64 + tx4] = make_float4(acc[i][4], acc[i][5], acc[i][6], acc[i][7]);
  }
}

// =====================================================================
// state: gather us/ue, LSTM step, r + gate for both suffixes. 1 block, 512 thr
// =====================================================================
__global__ void k_state(
    const float* __restrict__ U,
    const float* __restrict__ Wih, const float* __restrict__ Whh,
    const float* __restrict__ bih, const float* __restrict__ bhh,
    const float* __restrict__ Wr_s, const float* __restrict__ br_s,
    const float* __restrict__ Wg_s, const float* __restrict__ bg_s,
    const float* __restrict__ Wr_e, const float* __restrict__ br_e,
    const float* __restrict__ Wg_e, const float* __restrict__ bg_e,
    float* __restrict__ ws) {
  __shared__ float xs[512];
  __shared__ float hs[128];
  __shared__ float gs[512];
  __shared__ float ctx[640];
  __shared__ float logit[4];
  int t = threadIdx.x;
  int si = ((const int*)ws)[WS_SI];
  int ei = ((const int*)ws)[WS_EI];
  if (t < 256) xs[t] = U[(size_t)si * 256 + t];
  else         xs[t] = U[(size_t)ei * 256 + (t - 256)];
  if (t < 128) hs[t] = ws[WS_H + t];
  __syncthreads();
  // gates g[0..511]
  {
    float acc = bih[t] + bhh[t];
    const float* wr = Wih + (size_t)t * 512;
    for (int j = 0; j < 512; j += 4) {
      float4 w = *(const float4*)&wr[j];
      acc += w.x * xs[j] + w.y * xs[j+1] + w.z * xs[j+2] + w.w * xs[j+3];
    }
    const float* wh = Whh + (size_t)t * 128;
    for (int j = 0; j < 128; j += 4) {
      float4 w = *(const float4*)&wh[j];
      acc += w.x * hs[j] + w.y * hs[j+1] + w.z * hs[j+2] + w.w * hs[j+3];
    }
    gs[t] = acc;
  }
  __syncthreads();
  if (t < 128) {
    float ig = 1.f / (1.f + expf(-gs[t]));
    float fg = 1.f / (1.f + expf(-gs[128 + t]));
    float gg = tanhf(gs[256 + t]);
    float og = 1.f / (1.f + expf(-gs[384 + t]));
    float c2 = fg * ws[WS_C + t] + ig * gg;
    float h2 = og * tanhf(c2);
    ws[WS_C + t] = c2;
    ws[WS_H + t] = h2;
    ctx[t] = h2;
  }
  ctx[128 + t] = xs[t];          // t < 512 covers 128..639
  __syncthreads();
  if (t < 128) {
    float acc = br_s[t];
    const float* w = Wr_s + (size_t)t * 640;
    for (int j = 0; j < 640; j += 4) {
      float4 wv = *(const float4*)&w[j];
      acc += wv.x * ctx[j] + wv.y * ctx[j+1] + wv.z * ctx[j+2] + wv.w * ctx[j+3];
    }
    ws[WS_RS + t] = tanhf(acc);
  } else if (t < 256) {
    int i = t - 128;
    float acc = br_e[i];
    const float* w = Wr_e + (size_t)i * 640;
    for (int j = 0; j < 640; j += 4) {
      float4 wv = *(const float4*)&w[j];
      acc += wv.x * ctx[j] + wv.y * ctx[j+1] + wv.z * ctx[j+2] + wv.w * ctx[j+3];
    }
    ws[WS_RE + i] = tanhf(acc);
  } else if (t < 260) {
    int which = t - 256;                 // 0,1: s ; 2,3: e
    const float* Wg = (which < 2) ? Wg_s : Wg_e;
    const float* bg = (which < 2) ? bg_s : bg_e;
    int i = which & 1;
    float acc = bg[i];
    const float* w = Wg + (size_t)i * 640;
    for (int j = 0; j < 640; j += 4) {
      float4 wv = *(const float4*)&w[j];
      acc += wv.x * ctx[j] + wv.y * ctx[j+1] + wv.z * ctx[j+2] + wv.w * ctx[j+3];
    }
    logit[which] = acc;
  }
  __syncthreads();
  if (t == 0) {
    float a = logit[0], b = logit[1], mx = fmaxf(a, b);
    float ea = expf(a - mx), eb = expf(b - mx), s = ea + eb;
    ws[WS_GS + 0] = ea / s; ws[WS_GS + 1] = eb / s;
    a = logit[2]; b = logit[3]; mx = fmaxf(a, b);
    ea = expf(a - mx); eb = expf(b - mx); s = ea + eb;
    ws[WS_GS + 2] = ea / s; ws[WS_GS + 3] = eb / s;
  }
}

// =====================================================================
// rterm[suf][k][e] = be[k][e] + sum_j We[k][e][256+j] * r_suf[j]
// =====================================================================
__global__ void k_rterm(
    const float* __restrict__ We_s, const float* __restrict__ be_s,
    const float* __restrict__ We_e, const float* __restrict__ be_e,
    float* __restrict__ ws) {
  int gid = blockIdx.x * blockDim.x + threadIdx.x;   // 0..4095
  int suf = gid >> 11, rest = gid & 2047;
  const float* We = suf ? We_e : We_s;
  const float* be = suf ? be_e : be_s;
  const float* r  = ws + (suf ? WS_RE : WS_RS);
  const float* w  = We + (size_t)rest * 384 + 256;
  float acc = be[rest];
  for (int j = 0; j < 128; j += 4) {
    float4 wv = *(const float4*)&w[j];
    acc += wv.x * r[j] + wv.y * r[j+1] + wv.z * r[j+2] + wv.w * r[j+3];
  }
  ws[WS_RT + suf * 2048 + rest] = acc;
}

// =====================================================================
// score (from cached Z0): per 32-row tile: maxout+mix -> m1 ; m1@W2^T maxout
// -> m2 ; [m1|m2]@W3^T max -> ls.  grid (128, nsuf), 256 threads.
// =====================================================================
__global__ __launch_bounds__(256) void k_score(
    const float* __restrict__ z0_a, const float* __restrict__ z0_b,
    const float* __restrict__ W2_a, const float* __restrict__ b2_a,
    const float* __restrict__ W3_a, const float* __restrict__ b3_a,
    const float* __restrict__ W2_b, const float* __restrict__ b2_b,
    const float* __restrict__ W3_b, const float* __restrict__ b3_b,
    float* __restrict__ out_a, float* __restrict__ out_b,
    const float* __restrict__ ws, int suf0) {
  __shared__ float rterm[2048];
  __shared__ float m1[32][132];
  __shared__ float w2sT[32][132];
  __shared__ float m2[32][132];
  __shared__ float sj[32][8];

  int t = threadIdx.x;
  int y = blockIdx.y;
  int suf = suf0 + y;
  int m0 = blockIdx.x * 32;
  const float* z0 = y ? z0_b : z0_a;
  const float* W2 = y ? W2_b : W2_a;
  const float* b2 = y ? b2_b : b2_a;
  const float* W3 = y ? W3_b : W3_a;
  const float* b3 = y ? b3_b : b3_a;
  float*      outp = y ? out_b : out_a;
  float g0 = ws[WS_GS + suf * 2 + 0];
  float g1 = ws[WS_GS + suf * 2 + 1];
  const float* rt = ws + WS_RT + suf * 2048;
  for (int l = t; l < 2048; l += 256) rterm[l] = rt[l];
  __syncthreads();

  // phase 1: maxout over p, mix over k -> m1
  {
    int dd = t & 127, half = t >> 7;
    for (int rp = 0; rp < 16; ++rp) {
      int row = rp * 2 + half;
      int m = m0 + row;
      const float* zr0 = z0 + (size_t)m * 1024;
      const float* zr1 = z0 + (size_t)(MM + m) * 1024;
      float mx0 = NEG_INF, mx1 = NEG_INF;
#pragma unroll
      for (int pp = 0; pp < 8; ++pp) {
        mx0 = fmaxf(mx0, zr0[pp * 128 + dd] + rterm[pp * 128 + dd]);
        mx1 = fmaxf(mx1, zr1[pp * 128 + dd] + rterm[1024 + pp * 128 + dd]);
      }
      m1[row][dd] = g0 * mx0 + g1 * mx1;
    }
  }
  __syncthreads();

  // phase 2: v = m1 @ W2^T + b2, maxout over p -> m2
  int cg = t & 31, rg = t >> 5;
  int cg4 = cg * 4, rg4 = rg * 4;
  float m2acc[4][4];
#pragma unroll
  for (int i = 0; i < 4; ++i)
#pragma unroll
    for (int j = 0; j < 4; ++j) m2acc[i][j] = NEG_INF;

  for (int sp = 0; sp < 8; ++sp) {
    float acc[4][4];
#pragma unroll
    for (int j = 0; j < 4; ++j) {
      float bv = b2[sp * 128 + cg4 + j];
#pragma unroll
      for (int i = 0; i < 4; ++i) acc[i][j] = bv;
    }
    for (int fc = 0; fc < 4; ++fc) {
      __syncthreads();
      for (int l = t; l < 1024; l += 256) {
        int er = l >> 3, fq = l & 7;
        float4 v = *(const float4*)&W2[(size_t)(sp * 128 + er) * 128 + fc * 32 + fq * 4];
        w2sT[fq*4+0][er] = v.x; w2sT[fq*4+1][er] = v.y;
        w2sT[fq*4+2][er] = v.z; w2sT[fq*4+3][er] = v.w;
      }
      __syncthreads();
#pragma unroll
      for (int f = 0; f < 32; f += 4) {
        float4 b0v = *(const float4*)&w2sT[f+0][cg4];
        float4 b1v = *(const float4*)&w2sT[f+1][cg4];
        float4 b2v = *(const float4*)&w2sT[f+2][cg4];
        float4 b3v = *(const float4*)&w2sT[f+3][cg4];
        int fb = fc * 32 + f;
#pragma unroll
        for (int i = 0; i < 4; ++i) {
          float4 av = *(const float4*)&m1[rg4 + i][fb];
          acc[i][0] += av.x*b0v.x + av.y*b1v.x + av.z*b2v.x + av.w*b3v.x;
          acc[i][1] += av.x*b0v.y + av.y*b1v.y + av.z*b2v.y + av.w*b3v.y;
          acc[i][2] += av.x*b0v.z + av.y*b1v.z + av.z*b2v.z + av.w*b3v.z;
          acc[i][3] += av.x*b0v.w + av.y*b1v.w + av.z*b2v.w + av.w*b3v.w;
        }
      }
    }
#pragma unroll
    for (int i = 0; i < 4; ++i)
#pragma unroll
      for (int j = 0; j < 4; ++j) m2acc[i][j] = fmaxf(m2acc[i][j], acc[i][j]);
  }
  __syncthreads();
#pragma unroll
  for (int i = 0; i < 4; ++i)
#pragma unroll
    for (int j = 0; j < 4; ++j) m2[rg4 + i][cg4 + j] = m2acc[i][j];
  __syncthreads();

  // phase 3: s = [m1|m2] @ W3^T + b3, max over 8 -> ls
  {
    int row = t & 31, jp = t >> 5;
    const float* w3 = W3 + jp * 256;
    float acc = b3[jp];
    for (int f = 0; f < 128; f += 4) {
      float4 w = *(const float4*)&w3[f];
      acc += w.x*m1[row][f] + w.y*m1[row][f+1] + w.z*m1[row][f+2] + w.w*m1[row][f+3];
    }
    for (int f = 0; f < 128; f += 4) {
      float4 w = *(const float4*)&w3[128 + f];
      acc += w.x*m2[row][f] + w.y*m2[row][f+1] + w.z*m2[row][f+2] + w.w*m2[row][f+3];
    }
    sj[row][jp] = acc;
  }
  __syncthreads();
  if (t < 32) {
    float mx = sj[t][0];
#pragma unroll
    for (int j = 1; j < 8; ++j) mx = fmaxf(mx, sj[t][j]);
    outp[m0 + t] = mx;
  }
}

// =====================================================================
// slow fallback (tiny ws): one block per m, recompute z directly
// =====================================================================
__global__ void k_score_slow(
    const float* __restrict__ U,
    const float* __restrict__ We_a, const float* __restrict__ We_b,
    const float* __restrict__ W2_a, const float* __restrict__ b2_a,
    const float* __restrict__ W3_a, const float* __restrict__ b3_a,
    const float* __restrict__ W2_b, const float* __restrict__ b2_b,
    const float* __restrict__ W3_b, const float* __restrict__ b3_b,
    float* __restrict__ out_a, float* __restrict__ out_b,
    const float* __restrict__ ws, int suf0) {
  __shared__ float u[256];
  __shared__ float m1s[128];
  __shared__ float m2v[1024];
  __shared__ float m2s[128];
  __shared__ float sjs[8];
  int t = threadIdx.x;
  int m = blockIdx.x;
  int y = blockIdx.y;
  int suf = suf0 + y;
  const float* We = y ? We_b : We_a;
  const float* W2 = y ? W2_b : W2_a;
  const float* b2 = y ? b2_b : b2_a;
  const float* W3 = y ? W3_b : W3_a;
  const float* b3 = y ? b3_b : b3_a;
  float*     outp = y ? out_b : out_a;
  float g0 = ws[WS_GS + suf * 2 + 0];
  float g1 = ws[WS_GS + suf * 2 + 1];
  const float* rt = ws + WS_RT + suf * 2048;

  u[t] = U[(size_t)m * 256 + t];
  __syncthreads();
  if (t < 128) {
    float mx[2] = {NEG_INF, NEG_INF};
    for (int k = 0; k < 2; ++k) {
      for (int pp = 0; pp < 8; ++pp) {
        int e = k * 1024 + pp * 128 + t;
        const float* w = We + (size_t)e * 384;
        float acc = rt[e];
        for (int f = 0; f < 256; f += 4) {
          float4 wv = *(const float4*)&w[f];
          acc += wv.x*u[f] + wv.y*u[f+1] + wv.z*u[f+2] + wv.w*u[f+3];
        }
        mx[k] = fmaxf(mx[k], acc);
      }
    }
    m1s[t] = g0 * mx[0] + g1 * mx[1];
  }
  __syncthreads();
  for (int e = t; e < 1024; e += 256) {
    const float* w = W2 + (size_t)e * 128;
    float acc = b2[e];
    for (int f = 0; f < 128; f += 4) {
      float4 wv = *(const float4*)&w[f];
      acc += wv.x*m1s[f] + wv.y*m1s[f+1] + wv.z*m1s[f+2] + wv.w*m1s[f+3];
    }
    m2v[e] = acc;
  }
  __syncthreads();
  if (t < 128) {
    float mx = NEG_INF;
    for (int pp = 0; pp < 8; ++pp) mx = fmaxf(mx, m2v[pp * 128 + t]);
    m2s[t] = mx;
  }
  __syncthreads();
  if (t < 8) {
    const float* w3 = W3 + t * 256;
    float acc = b3[t];
    for (int f = 0; f < 128; ++f) acc += w3[f] * m1s[f];
    for (int f = 0; f < 128; ++f) acc += w3[128 + f] * m2s[f];
    sjs[t] = acc;
  }
  __syncthreads();
  if (t == 0) {
    float mx = sjs[0];
    for (int j = 1; j < 8; ++j) mx = fmaxf(mx, sjs[j]);
    outp[m] = mx;
  }
}

// =====================================================================
// argmax (first max index) over 4096 -> si/ei
// =====================================================================
__global__ void k_argmax(const float* __restrict__ out, int step, float* __restrict__ ws) {
  __shared__ float vals[256];
  __shared__ int   idxs[256];
  int y = blockIdx.x;                    // 0 = s -> si, 1 = e -> ei
  const float* ls = out + (size_t)y * (NSTEP * MM) + (size_t)step * MM;
  int t = threadIdx.x;
  float bv = NEG_INF; int bi = 0;
  for (int i = t; i < MM; i += 256) {
    float v = ls[i];
    if (v > bv) { bv = v; bi = i; }
  }
  vals[t] = bv; idxs[t] = bi;
  __syncthreads();
  for (int s = 128; s > 0; s >>= 1) {
    if (t < s) {
      float v2 = vals[t + s]; int i2 = idxs[t + s];
      if (v2 > vals[t] || (v2 == vals[t] && i2 < idxs[t])) { vals[t] = v2; idxs[t] = i2; }
    }
    __syncthreads();
  }
  if (t == 0) ((int*)ws)[y ? WS_EI : WS_SI] = idxs[0];
}

// =====================================================================
extern "C" void kernel_launch(void* const* d_in, const int* in_sizes, int n_in,
                              void* d_out, int out_size, void* d_ws, size_t ws_size,
                              hipStream_t stream) {
  const float* U    = (const float*)d_in[0];
  const float* Wih  = (const float*)d_in[1];
  const float* Whh  = (const float*)d_in[2];
  const float* bih  = (const float*)d_in[3];
  const float* bhh  = (const float*)d_in[4];
  const float* Wr_s = (const float*)d_in[5];
  const float* br_s = (const float*)d_in[6];
  const float* Wg_s = (const float*)d_in[7];
  const float* bg_s = (const float*)d_in[8];
  const float* We_s = (const float*)d_in[9];
  const float* be_s = (const float*)d_in[10];
  const float* W2_s = (const float*)d_in[11];
  const float* b2_s = (const float*)d_in[12];
  const float* W3_s = (const float*)d_in[13];
  const float* b3_s = (const float*)d_in[14];
  const float* Wr_e = (const float*)d_in[15];
  const float* br_e = (const float*)d_in[16];
  const float* Wg_e = (const float*)d_in[17];
  const float* bg_e = (const float*)d_in[18];
  const float* We_e = (const float*)d_in[19];
  const float* be_e = (const float*)d_in[20];
  const float* W2_e = (const float*)d_in[21];
  const float* b2_e = (const float*)d_in[22];
  const float* W3_e = (const float*)d_in[23];
  const float* b3_e = (const float*)d_in[24];
  float* out = (float*)d_out;
  float* ws  = (float*)d_ws;

  const size_t zhalf = (size_t)KK * MM * 1024;            // 8,388,608 floats per suffix
  const size_t needA = ((size_t)WS_Z0 + 2 * zhalf) * 4;   // ~67 MB
  const size_t needB = ((size_t)WS_Z0 + zhalf) * 4;       // ~34 MB
  int path = (ws_size >= needA) ? 0 : ((ws_size >= needB) ? 1 : 2);

  float* z0s = ws + WS_Z0;
  float* z0e = ws + WS_Z0 + ((path == 0) ? zhalf : 0);

  k_init<<<1, 256, 0, stream>>>(ws);
  if (path == 0) {
    k_z0<<<dim3(32, 8, 4), 256, 0, stream>>>(U, We_s, We_e, z0s, z0e, -1);
  }

  for (int step = 0; step < NSTEP; ++step) {
    k_state<<<1, 512, 0, stream>>>(U, Wih, Whh, bih, bhh,
                                   Wr_s, br_s, Wg_s, bg_s,
                                   Wr_e, br_e, Wg_e, bg_e, ws);
    k_rterm<<<16, 256, 0, stream>>>(We_s, be_s, We_e, be_e, ws);

    float* out_s = out + (size_t)step * MM;
    float* out_e = out + (size_t)NSTEP * MM + (size_t)step * MM;

    if (path == 0) {
      k_score<<<dim3(128, 2), 256, 0, stream>>>(
          z0s, z0e,
          W2_s, b2_s, W3_s, b3_s,
          W2_e, b2_e, W3_e, b3_e,
          out_s, out_e, ws, 0);
    } else if (path == 1) {
      k_z0<<<dim3(32, 8, 2), 256, 0, stream>>>(U, We_s, We_e, z0s, z0s, 0);
      k_score<<<dim3(128, 1), 256, 0, stream>>>(
          z0s, z0s,
          W2_s, b2_s, W3_s, b3_s,
          W2_s, b2_s, W3_s, b3_s,
          out_s, out_s, ws, 0);
      k_z0<<<dim3(32, 8, 2), 256, 0, stream>>>(U, We_s, We_e, z0s, z0s, 1);
      k_score<<<dim3(128, 1), 256, 0, stream>>>(
          z0s, z0s,
          W2_e, b2_e, W3_e, b3_e,
          W2_e, b2_e, W3_e, b3_e,
          out_e, out_e, ws, 1);
    } else {
      k_score_slow<<<dim3(MM, 2), 256, 0, stream>>>(
          U, We_s, We_e,
          W2_s, b2_s, W3_s, b3_s,
          W2_e, b2_e, W3_e, b3_e,
          out_s, out_e, ws, 0);
    }

    k_argmax<<<2, 256, 0, stream>>>(out, step, ws);
  }
}